// Round 11
// baseline (476.679 us; speedup 1.0000x reference)
//
#include <hip/hip_runtime.h>

typedef __attribute__((ext_vector_type(8))) short bf16x8;
typedef __attribute__((ext_vector_type(4))) float f32x4;
typedef __attribute__((ext_vector_type(2))) float f32x2;
typedef __attribute__((ext_vector_type(4))) unsigned int u32x4;

static __device__ __forceinline__ unsigned short f2bf(float f) {
    union { float f; unsigned u; } v; v.f = f;
    return (unsigned short)((v.u + 0x7FFFu + ((v.u >> 16) & 1u)) >> 16);
}

static __device__ __forceinline__ void g2l16(const void* g, void* l) {
    __builtin_amdgcn_global_load_lds(
        (const __attribute__((address_space(1))) unsigned int*)g,
        (__attribute__((address_space(3))) unsigned int*)l, 16, 0, 0);
}

// Wp[ch=4][rs=9][oc=256][cw=32] bf16, value = weight[oc][ch*32+cw][r][s] * wscale
__global__ void prep_weights(const float* __restrict__ w, unsigned short* __restrict__ wp) {
    int t = blockIdx.x * 256 + threadIdx.x;      // 0..294911
    const float wscale = 0.02946278254943948f;   // 1/sqrt(3*3*128)
    int cw = t & 31;
    int oc = (t >> 5) & 255;
    int cr = t >> 13;          // 0..35
    int ch = cr / 9;
    int rs = cr - ch * 9;
    int r  = rs / 3;
    int s  = rs - r * 3;
    int c  = ch * 32 + cw;
    wp[t] = f2bf(w[((oc * 128 + c) * 3 + r) * 3 + s] * wscale);
}

// ================= blur_rec: per-tile swizzled records =================
// bm[((n*128+tile)*4+cg)] = 35904B record = LDS image: granule(row,J) at
// (row*33 + (J^((J>>1)&1)))*64, ch c at byte ((c>>3 ^ ((J>>2)&3))<<4) + (c&7)*2.
#define BPX(ROW) {                                                             \
    int _xr = xr0 + (ROW);                                                     \
    int _xc = _xr < 0 ? 0 : (_xr > 255 ? 255 : _xr);                           \
    float _rm = (_xr == _xc) ? 0.125f : 0.0f;                                  \
    const float* _p0 = pq0 + (_xc << 8);                                       \
    const float* _p1 = pq1 + (_xc << 8);                                       \
    f32x4 _l0, _l1; f32x2 _h0, _h1;                                            \
    __builtin_memcpy(&_l0, _p0, 16); __builtin_memcpy(&_h0, _p0 + 4, 8);       \
    __builtin_memcpy(&_l1, _p1, 16); __builtin_memcpy(&_h1, _p1 + 4, 8);       \
    hA0[(ROW) & 3] = (_l0.x + 3.f * (_l0.y + _l0.z) + _l0.w) * _rm;            \
    hB0[(ROW) & 3] = (_l0.y + 3.f * (_l0.z + _l0.w) + _h0.x) * _rm;            \
    hC0[(ROW) & 3] = (_l0.z + 3.f * (_l0.w + _h0.x) + _h0.y) * _rm;            \
    hA1[(ROW) & 3] = (_l1.x + 3.f * (_l1.y + _l1.z) + _l1.w) * _rm;            \
    hB1[(ROW) & 3] = (_l1.y + 3.f * (_l1.z + _l1.w) + _h1.x) * _rm;            \
    hC1[(ROW) & 3] = (_l1.z + 3.f * (_l1.w + _h1.x) + _h1.y) * _rm;            \
}
#define BPS(ROW) {                                                             \
    int _xr = xr0 + (ROW);                                                     \
    float a0=0.f,a1=0.f,a2=0.f,a3=0.f,a4=0.f,a5=0.f;                           \
    float b0=0.f,b1=0.f,b2=0.f,b3=0.f,b4=0.f,b5=0.f;                           \
    if ((unsigned)_xr < 256u) {                                                \
        const float* _p0 = pq0 + (_xr << 8);                                   \
        const float* _p1 = pq1 + (_xr << 8);                                   \
        if ((unsigned)(wc + 0) < 256u) { a0 = _p0[0]; b0 = _p1[0]; }           \
        if ((unsigned)(wc + 1) < 256u) { a1 = _p0[1]; b1 = _p1[1]; }           \
        if ((unsigned)(wc + 2) < 256u) { a2 = _p0[2]; b2 = _p1[2]; }           \
        if ((unsigned)(wc + 3) < 256u) { a3 = _p0[3]; b3 = _p1[3]; }           \
        if ((unsigned)(wc + 4) < 256u) { a4 = _p0[4]; b4 = _p1[4]; }           \
        if ((unsigned)(wc + 5) < 256u) { a5 = _p0[5]; b5 = _p1[5]; }           \
    }                                                                          \
    hA0[(ROW) & 3] = (a0 + 3.f * (a1 + a2) + a3) * 0.125f;                     \
    hB0[(ROW) & 3] = (a1 + 3.f * (a2 + a3) + a4) * 0.125f;                     \
    hC0[(ROW) & 3] = (a2 + 3.f * (a3 + a4) + a5) * 0.125f;                     \
    hA1[(ROW) & 3] = (b0 + 3.f * (b1 + b2) + b3) * 0.125f;                     \
    hB1[(ROW) & 3] = (b1 + 3.f * (b2 + b3) + b4) * 0.125f;                     \
    hC1[(ROW) & 3] = (b2 + 3.f * (b3 + b4) + b5) * 0.125f;                     \
}
#define BPV(ROW) {                                                             \
    float vA0 = (hA0[(ROW-3)&3] + 3.f*(hA0[(ROW-2)&3]+hA0[(ROW-1)&3]) + hA0[(ROW)&3]) * 0.125f; \
    float vA1 = (hA1[(ROW-3)&3] + 3.f*(hA1[(ROW-2)&3]+hA1[(ROW-1)&3]) + hA1[(ROW)&3]) * 0.125f; \
    float vB0 = (hB0[(ROW-3)&3] + 3.f*(hB0[(ROW-2)&3]+hB0[(ROW-1)&3]) + hB0[(ROW)&3]) * 0.125f; \
    float vB1 = (hB1[(ROW-3)&3] + 3.f*(hB1[(ROW-2)&3]+hB1[(ROW-1)&3]) + hB1[(ROW)&3]) * 0.125f; \
    unsigned _rb = (unsigned)(ROW - 3) * 2112u;                                \
    *(unsigned*)(blds + _rb + o0) = (unsigned)f2bf(vA0) | ((unsigned)f2bf(vA1) << 16); \
    *(unsigned*)(blds + _rb + o1) = (unsigned)f2bf(vB0) | ((unsigned)f2bf(vB1) << 16); \
    if (a15) {                                                                 \
        float vC0 = (hC0[(ROW-3)&3] + 3.f*(hC0[(ROW-2)&3]+hC0[(ROW-1)&3]) + hC0[(ROW)&3]) * 0.125f; \
        float vC1 = (hC1[(ROW-3)&3] + 3.f*(hC1[(ROW-2)&3]+hC1[(ROW-1)&3]) + hC1[(ROW)&3]) * 0.125f; \
        *(unsigned*)(blds + _rb + o2) = (unsigned)f2bf(vC0) | ((unsigned)f2bf(vC1) << 16); \
    }                                                                          \
}
#define BPF(ROW) BPX(ROW) BPV(ROW)
#define BPP(ROW) BPS(ROW) BPV(ROW)

__global__ __launch_bounds__(256, 4)
void blur_rec(const float* __restrict__ x, unsigned char* __restrict__ bm) {
    __shared__ __align__(16) unsigned char blds[35904];
    const int bx   = blockIdx.x;              // ((n*128 + tile)*4 + cg)
    const int cg   = bx & 3;
    const int tile = (bx >> 2) & 127;
    const int n    = bx >> 9;
    const int u0   = (tile >> 3) * 8;
    const int v0   = (tile & 7) * 16;
    const int tid  = threadIdx.x;
    const int a    = tid & 15;                // col pair -> J 2a, 2a+1 (+32 if a15)
    const int chp  = tid >> 4;                // channel pair (2chp, 2chp+1)
    const bool a15 = (a == 15);
    const int wc   = 2 * v0 - 2 + 2 * a;
    const bool edge = (v0 == 0 && a == 0) || (v0 == 112 && a15);
    const float* pq0 = x + (size_t)(n * 128 + cg * 32 + 2 * chp) * 65536 + wc;
    const float* pq1 = pq0 + 65536;
    const int xr0 = 2 * u0 - 2;

    const int J0 = 2 * a, J1 = 2 * a + 1;
    const unsigned cb2 = (unsigned)(chp & 3) * 4u;
    const unsigned o0 = (unsigned)((J0 ^ ((J0 >> 1) & 1)) * 64) + ((((unsigned)chp >> 2) ^ (((unsigned)J0 >> 2) & 3u)) << 4) + cb2;
    const unsigned o1 = (unsigned)((J1 ^ ((J1 >> 1) & 1)) * 64) + ((((unsigned)chp >> 2) ^ (((unsigned)J1 >> 2) & 3u)) << 4) + cb2;
    const unsigned o2 = 2048u + (((unsigned)chp >> 2) << 4) + cb2;

    {
        float hA0[4], hB0[4], hC0[4], hA1[4], hB1[4], hC1[4];
        if (!edge) {
            BPX(0) BPX(1) BPX(2)
            BPF(3)  BPF(4)  BPF(5)  BPF(6)  BPF(7)  BPF(8)  BPF(9)  BPF(10)
            BPF(11) BPF(12) BPF(13) BPF(14) BPF(15) BPF(16) BPF(17) BPF(18) BPF(19)
        } else {
            BPS(0) BPS(1) BPS(2)
            BPP(3)  BPP(4)  BPP(5)  BPP(6)  BPP(7)  BPP(8)  BPP(9)  BPP(10)
            BPP(11) BPP(12) BPP(13) BPP(14) BPP(15) BPP(16) BPP(17) BPP(18) BPP(19)
        }
    }
    __syncthreads();
    // coalesced dump of the finished record
    unsigned char* dst = bm + (size_t)bx * 35904u;
    #pragma unroll
    for (int k = 0; k < 8; ++k)
        *(u32x4*)(dst + (unsigned)(tid + 256 * k) * 16u) =
            *(const u32x4*)(blds + (unsigned)(tid + 256 * k) * 16u);
    if (tid < 196)
        *(u32x4*)(dst + (unsigned)(tid + 2048) * 16u) =
            *(const u32x4*)(blds + (unsigned)(tid + 2048) * 16u);
}

// ---------------- stage 2: MFMA conv; 8 waves = 8 oc-blocks, acc[8][2] ----------------
#define MF __builtin_amdgcn_mfma_f32_16x16x32_bf16
#define WLOAD2(S0, S1, KOFF) {                                                 \
    const unsigned short* _wn = wbase + (size_t)(KOFF) * 8192;                 \
    S0 = *(const bf16x8*)(_wn); S1 = *(const bf16x8*)(_wn + 512);              \
}
#define CSTEP8(BUF, ADRS, R, S0, S1) {                                         \
    const unsigned char* _ab = lds + (BUF) + (ADRS) + (R) * 2112;              \
    bf16x8 a0 = *(const bf16x8*)(_ab);                                         \
    bf16x8 a1 = *(const bf16x8*)(_ab +  4224);                                 \
    bf16x8 a2 = *(const bf16x8*)(_ab +  8448);                                 \
    bf16x8 a3 = *(const bf16x8*)(_ab + 12672);                                 \
    bf16x8 a4 = *(const bf16x8*)(_ab + 16896);                                 \
    bf16x8 a5 = *(const bf16x8*)(_ab + 21120);                                 \
    bf16x8 a6 = *(const bf16x8*)(_ab + 25344);                                 \
    bf16x8 a7 = *(const bf16x8*)(_ab + 29568);                                 \
    __builtin_amdgcn_s_setprio(1);                                             \
    acc[0][0]=MF(a0,S0,acc[0][0],0,0,0); acc[0][1]=MF(a0,S1,acc[0][1],0,0,0);  \
    acc[1][0]=MF(a1,S0,acc[1][0],0,0,0); acc[1][1]=MF(a1,S1,acc[1][1],0,0,0);  \
    acc[2][0]=MF(a2,S0,acc[2][0],0,0,0); acc[2][1]=MF(a2,S1,acc[2][1],0,0,0);  \
    acc[3][0]=MF(a3,S0,acc[3][0],0,0,0); acc[3][1]=MF(a3,S1,acc[3][1],0,0,0);  \
    acc[4][0]=MF(a4,S0,acc[4][0],0,0,0); acc[4][1]=MF(a4,S1,acc[4][1],0,0,0);  \
    acc[5][0]=MF(a5,S0,acc[5][0],0,0,0); acc[5][1]=MF(a5,S1,acc[5][1],0,0,0);  \
    acc[6][0]=MF(a6,S0,acc[6][0],0,0,0); acc[6][1]=MF(a6,S1,acc[6][1],0,0,0);  \
    acc[7][0]=MF(a7,S0,acc[7][0],0,0,0); acc[7][1]=MF(a7,S1,acc[7][1],0,0,0);  \
    __builtin_amdgcn_s_setprio(0);                                             \
}
#define CHUNK8(BUF, BASE, A0,A1, B0,B1)                                        \
    CSTEP8(BUF, adr0, 0, A0,A1) WLOAD2(A0,A1, (BASE)+2)                        \
    CSTEP8(BUF, adr1, 0, B0,B1) WLOAD2(B0,B1, (BASE)+3)                        \
    CSTEP8(BUF, adr2, 0, A0,A1) WLOAD2(A0,A1, (BASE)+4)                        \
    CSTEP8(BUF, adr0, 1, B0,B1) WLOAD2(B0,B1, (BASE)+5)                        \
    CSTEP8(BUF, adr1, 1, A0,A1) WLOAD2(A0,A1, (BASE)+6)                        \
    CSTEP8(BUF, adr2, 1, B0,B1) WLOAD2(B0,B1, (BASE)+7)                        \
    CSTEP8(BUF, adr0, 2, A0,A1) WLOAD2(A0,A1, (BASE)+8)                        \
    CSTEP8(BUF, adr1, 2, B0,B1) WLOAD2(B0,B1, (BASE)+9)                        \
    CSTEP8(BUF, adr2, 2, A0,A1) WLOAD2(A0,A1, (BASE)+10)
#define CHUNK8_LAST(BUF, BASE, A0,A1, B0,B1)                                   \
    CSTEP8(BUF, adr0, 0, A0,A1) WLOAD2(A0,A1, (BASE)+2)                        \
    CSTEP8(BUF, adr1, 0, B0,B1) WLOAD2(B0,B1, (BASE)+3)                        \
    CSTEP8(BUF, adr2, 0, A0,A1) WLOAD2(A0,A1, (BASE)+4)                        \
    CSTEP8(BUF, adr0, 1, B0,B1) WLOAD2(B0,B1, (BASE)+5)                        \
    CSTEP8(BUF, adr1, 1, A0,A1) WLOAD2(A0,A1, (BASE)+6)                        \
    CSTEP8(BUF, adr2, 1, B0,B1) WLOAD2(B0,B1, (BASE)+7)                        \
    CSTEP8(BUF, adr0, 2, A0,A1) WLOAD2(A0,A1, (BASE)+8)                        \
    CSTEP8(BUF, adr1, 2, B0,B1)                                                \
    CSTEP8(BUF, adr2, 2, A0,A1)

__global__ __launch_bounds__(512, 4)
void conv_stage2(const unsigned char* __restrict__ bm, const unsigned short* __restrict__ wp,
                 const float* __restrict__ bias, float* __restrict__ out) {
    __shared__ __align__(16) unsigned char lds[2 * 35904];

    const int bx = blockIdx.x;
    const int n  = bx >> 7;
    const int tt = bx & 127;
    const int u0 = (tt >> 3) * 8;
    const int v0 = (tt & 7) * 16;

    const int tid  = threadIdx.x;
    const int lane = tid & 63;
    const int wid  = tid >> 6;       // oc block: oc in [wid*32, wid*32+32)
    const int g    = lane >> 4;
    const int wq   = lane & 15;

    const unsigned char* rec = bm + (size_t)((n * 128 + tt) * 4) * 35904u;

#define STAGE(BUF, CG) {                                                       \
    const unsigned char* _src = rec + (size_t)(CG) * 35904u;                   \
    _Pragma("unroll")                                                          \
    for (int k = 0; k < 4; ++k)                                                \
        g2l16(_src + (unsigned)(tid + 512 * k) * 16u,                          \
              lds + (BUF) + (unsigned)(tid + 512 * k) * 16u);                  \
    if (tid < 196)                                                             \
        g2l16(_src + (unsigned)(tid + 2048) * 16u,                             \
              lds + (BUF) + (unsigned)(tid + 2048) * 16u);                     \
}

    // A-frag bases per s (granule swizzle bj^((bj>>1)&1), slot g^((bj>>2)&3))
    unsigned adr0, adr1, adr2;
    {
        #pragma unroll
        for (int s = 0; s < 3; ++s) {
            unsigned bj = 2u * (unsigned)wq + (unsigned)s;
            unsigned av = (bj ^ ((bj >> 1) & 1u)) * 64u
                        + (((unsigned)g ^ ((bj >> 2) & 3u)) << 4);
            if (s == 0) adr0 = av; else if (s == 1) adr1 = av; else adr2 = av;
        }
    }

    const unsigned short* wbase = wp + (size_t)(wid * 32 + wq) * 32 + g * 8;
    bf16x8 WA0, WA1, WB0, WB1;
    WLOAD2(WA0, WA1, 0)
    WLOAD2(WB0, WB1, 1)

    f32x4 acc[8][2];
    #pragma unroll
    for (int i = 0; i < 8; ++i) {
        acc[i][0] = (f32x4){0.f, 0.f, 0.f, 0.f};
        acc[i][1] = (f32x4){0.f, 0.f, 0.f, 0.f};
    }

    STAGE(0, 0)
    __syncthreads();

    STAGE(35904, 1)
    CHUNK8(0, 0, WA0, WA1, WB0, WB1)
    __syncthreads();

    STAGE(0, 2)
    CHUNK8(35904, 9, WB0, WB1, WA0, WA1)
    __syncthreads();

    STAGE(35904, 3)
    CHUNK8(0, 18, WA0, WA1, WB0, WB1)
    __syncthreads();

    CHUNK8_LAST(35904, 27, WB0, WB1, WA0, WA1)

    // epilogue: u = u0 + mf, v = v0 + 4g + i, oc = wid*32 + nf*16 + wq
    const float gain = 1.4142135623730951f;
    #pragma unroll
    for (int nf = 0; nf < 2; ++nf) {
        const int ocg = wid * 32 + nf * 16 + wq;
        const float bb = bias[ocg];
        #pragma unroll
        for (int mf = 0; mf < 8; ++mf) {
            f32x4 o;
            #pragma unroll
            for (int i = 0; i < 4; ++i) {
                float z = acc[mf][nf][i] + bb;
                z = (z >= 0.f ? z : 0.2f * z) * gain;
                o[i] = fminf(fmaxf(z, -256.f), 256.f);
            }
            *(f32x4*)(out + (((size_t)n * 256 + ocg) * 128 + (u0 + mf)) * 128 + v0 + 4 * g) = o;
        }
    }
}

// ======================= Fallback: proven R5 fused kernel =======================
#define FROW(row) {                                                            \
    int xr  = xr0 + (row);                                                     \
    int xrc = xr < 0 ? 0 : (xr > 255 ? 255 : xr);                              \
    float rm = (xr == xrc) ? 0.125f : 0.0f;                                    \
    const float* p = q + (xrc << 8);                                           \
    f32x4 lo; f32x2 hi;                                                        \
    __builtin_memcpy(&lo, p, 16);                                              \
    __builtin_memcpy(&hi, p + 4, 8);                                           \
    hA[(row) & 3] = (lo.x + 3.f * (lo.y + lo.z) + lo.w) * rm;                  \
    hB[(row) & 3] = (lo.y + 3.f * (lo.z + lo.w) + hi.x) * rm;                  \
    hC[(row) & 3] = (lo.z + 3.f * (lo.w + hi.x) + hi.y) * rm;                  \
}
#define SROW(row) {                                                            \
    int xr = xr0 + (row);                                                      \
    float wv0=0.f,wv1=0.f,wv2=0.f,wv3=0.f,wv4=0.f,wv5=0.f;                     \
    if ((unsigned)xr < 256u) {                                                 \
        const float* p = q + (xr << 8);                                        \
        if ((unsigned)(wc + 0) < 256u) wv0 = p[0];                             \
        if ((unsigned)(wc + 1) < 256u) wv1 = p[1];                             \
        if ((unsigned)(wc + 2) < 256u) wv2 = p[2];                             \
        if ((unsigned)(wc + 3) < 256u) wv3 = p[3];                             \
        if ((unsigned)(wc + 4) < 256u) wv4 = p[4];                             \
        if ((unsigned)(wc + 5) < 256u) wv5 = p[5];                             \
    }                                                                          \
    hA[(row) & 3] = (wv0 + 3.f * (wv1 + wv2) + wv3) * 0.125f;                  \
    hB[(row) & 3] = (wv1 + 3.f * (wv2 + wv3) + wv4) * 0.125f;                  \
    hC[(row) & 3] = (wv2 + 3.f * (wv3 + wv4) + wv5) * 0.125f;                  \
}
#define VROW(row) {                                                            \
    float bv0 = (hA[(row - 3) & 3] + 3.f * (hA[(row - 2) & 3] + hA[(row - 1) & 3]) + hA[(row) & 3]) * 0.125f; \
    float bv1 = (hB[(row - 3) & 3] + 3.f * (hB[(row - 2) & 3] + hB[(row - 1) & 3]) + hB[(row) & 3]) * 0.125f; \
    unsigned rb = (unsigned)(row - 3) * 2640u;                                 \
    *(unsigned short*)(flds + rb + o0) = f2bf(bv0);                            \
    *(unsigned short*)(flds + rb + o1) = f2bf(bv1);                            \
    if (a == 15) {                                                             \
        float bv2 = (hC[(row - 3) & 3] + 3.f * (hC[(row - 2) & 3] + hC[(row - 1) & 3]) + hC[(row) & 3]) * 0.125f; \
        *(unsigned short*)(flds + rb + o2) = f2bf(bv2);                        \
    }                                                                          \
}
__global__ __launch_bounds__(512, 4)
void conv_blur_mfma(const float* __restrict__ x, const unsigned short* __restrict__ wp,
                    const float* __restrict__ bias, float* __restrict__ out) {
    __shared__ __align__(16) unsigned char flds[17 * 33 * 80];
    const int bx = blockIdx.x;
    const int n  = bx >> 7;
    const int tt = bx & 127;
    const int u0 = (tt >> 3) * 8;
    const int v0 = (tt & 7) * 16;
    const int tid  = threadIdx.x;
    const int lane = tid & 63;
    const int wid  = tid >> 6;
    const int wm   = wid >> 2;
    const int wn   = wid & 3;
    const int g    = lane >> 4;
    const int wq   = lane & 15;
    const int a   = tid & 15;
    const int chl = tid >> 4;
    const int wc  = 2 * v0 - 2 + 2 * a;
    const bool edge = (v0 == 0 && a == 0) || (v0 == 112 && a == 15);
    const float* planeBase = x + (size_t)(n * 128 + chl) * 65536;
    const int xr0 = 2 * u0 - 2;
    const unsigned chpart = (unsigned)(((chl >> 1) & 3) * 4 + (chl & 1) * 2);
    const unsigned q4 = (unsigned)(chl >> 3);
    const int c0 = 2 * a;
    const unsigned o0 = (unsigned)(c0 + 0) * 80u + ((q4 ^ (((unsigned)(c0 + 0) >> 3) & 3u)) << 4) + chpart;
    const unsigned o1 = (unsigned)(c0 + 1) * 80u + ((q4 ^ (((unsigned)(c0 + 1) >> 3) & 3u)) << 4) + chpart;
    const unsigned o2 = (unsigned)(c0 + 2) * 80u + ((q4 ^ (((unsigned)(c0 + 2) >> 3) & 3u)) << 4) + chpart;
    const unsigned short* wpL = wp + (size_t)(wn * 64 + wq) * 32 + g * 8;
    f32x4 acc[4][4];
    #pragma unroll
    for (int i = 0; i < 4; ++i)
        #pragma unroll
        for (int j = 0; j < 4; ++j)
            acc[i][j] = (f32x4){0.f, 0.f, 0.f, 0.f};
    for (int ch = 0; ch < 4; ++ch) {
        const float* q = planeBase + (size_t)ch * 32 * 65536 + wc;
        float hA[4], hB[4], hC[4];
        if (!edge) { FROW(0) FROW(1) FROW(2) }
        else       { SROW(0) SROW(1) SROW(2) }
        __syncthreads();
        if (!edge) {
            #pragma unroll
            for (int row = 3; row < 20; ++row) { FROW(row) VROW(row) }
        } else {
            #pragma unroll
            for (int row = 3; row < 20; ++row) { SROW(row) VROW(row) }
        }
        __syncthreads();
        const unsigned short* wpc = wpL + (size_t)ch * 9 * 8192;
        #pragma unroll 1
        for (int r = 0; r < 3; ++r) {
            #pragma unroll 1
            for (int s = 0; s < 3; ++s) {
                bf16x8 b0 = *(const bf16x8*)(wpc + 0 * 512);
                bf16x8 b1 = *(const bf16x8*)(wpc + 1 * 512);
                bf16x8 b2 = *(const bf16x8*)(wpc + 2 * 512);
                bf16x8 b3 = *(const bf16x8*)(wpc + 3 * 512);
                wpc += 8192;
                int bj = 2 * wq + s;
                unsigned cb = (unsigned)bj * 80u + ((unsigned)(g ^ ((bj >> 3) & 3)) << 4);
                #pragma unroll
                for (int mf = 0; mf < 4; ++mf) {
                    int bi = 2 * (wm * 4 + mf) + r;
                    bf16x8 afrag = *(const bf16x8*)(flds + (unsigned)bi * 2640u + cb);
                    acc[mf][0] = MF(afrag, b0, acc[mf][0], 0, 0, 0);
                    acc[mf][1] = MF(afrag, b1, acc[mf][1], 0, 0, 0);
                    acc[mf][2] = MF(afrag, b2, acc[mf][2], 0, 0, 0);
                    acc[mf][3] = MF(afrag, b3, acc[mf][3], 0, 0, 0);
                }
            }
        }
    }
    const float gain = 1.4142135623730951f;
    #pragma unroll
    for (int nf = 0; nf < 4; ++nf) {
        int ocg = wn * 64 + nf * 16 + wq;
        float bv = bias[ocg];
        #pragma unroll
        for (int mf = 0; mf < 4; ++mf) {
            int u = u0 + wm * 4 + mf;
            f32x4 o;
            #pragma unroll
            for (int i = 0; i < 4; ++i) {
                float z = acc[mf][nf][i] + bv;
                z = (z >= 0.f ? z : 0.2f * z) * gain;
                o[i] = fminf(fmaxf(z, -256.f), 256.f);
            }
            *(f32x4*)(out + (((size_t)n * 256 + ocg) * 128 + u) * 128 + v0 + 4 * g) = o;
        }
    }
}

extern "C" void kernel_launch(void* const* d_in, const int* in_sizes, int n_in,
                              void* d_out, int out_size, void* d_ws, size_t ws_size,
                              hipStream_t stream) {
    const float* x    = (const float*)d_in[0];
    const float* w    = (const float*)d_in[1];
    const float* bias = (const float*)d_in[2];
    unsigned short* wp = (unsigned short*)d_ws;           // 589,824 B
    float* out = (float*)d_out;

    const size_t BM_BYTES = (size_t)8192 * 35904u;        // 294,076,416
    const size_t NEED = 589824u + BM_BYTES;
    prep_weights<<<1152, 256, 0, stream>>>(w, wp);
    if (ws_size >= NEED) {
        unsigned char* bm = (unsigned char*)d_ws + 589824;
        blur_rec<<<8192, 256, 0, stream>>>(x, bm);
        conv_stage2<<<2048, 512, 0, stream>>>(bm, wp, bias, out);
    } else {
        conv_blur_mfma<<<2048, 512, 0, stream>>>(x, wp, bias, out);
    }
}

// Round 12
// 413.479 us; speedup vs baseline: 1.1528x; 1.1528x over previous
//
#include <hip/hip_runtime.h>

typedef __attribute__((ext_vector_type(8))) short bf16x8;
typedef __attribute__((ext_vector_type(4))) float f32x4;
typedef __attribute__((ext_vector_type(2))) float f32x2;
typedef __attribute__((ext_vector_type(4))) unsigned int u32x4;

static __device__ __forceinline__ unsigned short f2bf(float f) {
    union { float f; unsigned u; } v; v.f = f;
    return (unsigned short)((v.u + 0x7FFFu + ((v.u >> 16) & 1u)) >> 16);
}

static __device__ __forceinline__ void g2l16(const void* g, void* l) {
    __builtin_amdgcn_global_load_lds(
        (const __attribute__((address_space(1))) unsigned int*)g,
        (__attribute__((address_space(3))) unsigned int*)l, 16, 0, 0);
}

// Wp[ch=4][rs=9][oc=256][cw=32] bf16, value = weight[oc][ch*32+cw][r][s] * wscale
__global__ void prep_weights(const float* __restrict__ w, unsigned short* __restrict__ wp) {
    int t = blockIdx.x * 256 + threadIdx.x;      // 0..294911
    const float wscale = 0.02946278254943948f;   // 1/sqrt(3*3*128)
    int cw = t & 31;
    int oc = (t >> 5) & 255;
    int cr = t >> 13;          // 0..35
    int ch = cr / 9;
    int rs = cr - ch * 9;
    int r  = rs / 3;
    int s  = rs - r * 3;
    int c  = ch * 32 + cw;
    wp[t] = f2bf(w[((oc * 128 + c) * 3 + r) * 3 + s] * wscale);
}

// ================= blur_rec v2: branchless, half-LDS double-dump =================
// Record layout (35904 B, = stage2's LDS image): granule(row,J) at (row*33 + (J^((J>>1)&1)))*64,
// ch c at byte (((c>>3) ^ ((J>>2)&3))<<4) + (c&7)*2. 17 rows x 33 J-granules.
// Thread (chp, a): channels 2chp,2chp+1; cols J=2a,2a+1 (+J=32 if a==15).
#define BRW(ROW) {                                                             \
    int _xr = xr0 + (ROW);                                                     \
    int _xc = _xr < 0 ? 0 : (_xr > 255 ? 255 : _xr);                           \
    float _rm = (_xr == _xc) ? 0.125f : 0.0f;                                  \
    const float* _q0 = p0lo + (_xc << 8);                                      \
    const float* _h0p = p0hi + (_xc << 8);                                     \
    const float* _q1 = p1lo + (_xc << 8);                                      \
    const float* _h1p = p1hi + (_xc << 8);                                     \
    f32x4 _l0, _l1; f32x2 _h0, _h1;                                            \
    __builtin_memcpy(&_l0, _q0, 16); __builtin_memcpy(&_h0, _h0p, 8);          \
    __builtin_memcpy(&_l1, _q1, 16); __builtin_memcpy(&_h1, _h1p, 8);          \
    float w00 = eL ? 0.f : _l0.x,  w01 = eL ? 0.f : _l0.y;                     \
    float w02 = eL ? _l0.x : _l0.z, w03 = eL ? _l0.y : _l0.w;                  \
    float w04 = eR ? 0.f : (eL ? _l0.z : _h0.x);                               \
    float w05 = eR ? 0.f : (eL ? _l0.w : _h0.y);                               \
    float w10 = eL ? 0.f : _l1.x,  w11 = eL ? 0.f : _l1.y;                     \
    float w12 = eL ? _l1.x : _l1.z, w13 = eL ? _l1.y : _l1.w;                  \
    float w14 = eR ? 0.f : (eL ? _l1.z : _h1.x);                               \
    float w15 = eR ? 0.f : (eL ? _l1.w : _h1.y);                               \
    hA0[(ROW) & 3] = (w00 + 3.f * (w01 + w02) + w03) * _rm;                    \
    hB0[(ROW) & 3] = (w01 + 3.f * (w02 + w03) + w04) * _rm;                    \
    hC0[(ROW) & 3] = (w02 + 3.f * (w03 + w04) + w05) * _rm;                    \
    hA1[(ROW) & 3] = (w10 + 3.f * (w11 + w12) + w13) * _rm;                    \
    hB1[(ROW) & 3] = (w11 + 3.f * (w12 + w13) + w14) * _rm;                    \
    hC1[(ROW) & 3] = (w12 + 3.f * (w13 + w14) + w15) * _rm;                    \
}
#define BWV(ROW, LBASE) {                                                      \
    float vA0 = (hA0[(ROW-3)&3] + 3.f*(hA0[(ROW-2)&3]+hA0[(ROW-1)&3]) + hA0[(ROW)&3]) * 0.125f; \
    float vA1 = (hA1[(ROW-3)&3] + 3.f*(hA1[(ROW-2)&3]+hA1[(ROW-1)&3]) + hA1[(ROW)&3]) * 0.125f; \
    float vB0 = (hB0[(ROW-3)&3] + 3.f*(hB0[(ROW-2)&3]+hB0[(ROW-1)&3]) + hB0[(ROW)&3]) * 0.125f; \
    float vB1 = (hB1[(ROW-3)&3] + 3.f*(hB1[(ROW-2)&3]+hB1[(ROW-1)&3]) + hB1[(ROW)&3]) * 0.125f; \
    unsigned _rb = (unsigned)(LBASE) * 2112u;                                  \
    *(unsigned*)(blds + _rb + o0) = (unsigned)f2bf(vA0) | ((unsigned)f2bf(vA1) << 16); \
    *(unsigned*)(blds + _rb + o1) = (unsigned)f2bf(vB0) | ((unsigned)f2bf(vB1) << 16); \
    if (a15) {                                                                 \
        float vC0 = (hC0[(ROW-3)&3] + 3.f*(hC0[(ROW-2)&3]+hC0[(ROW-1)&3]) + hC0[(ROW)&3]) * 0.125f; \
        float vC1 = (hC1[(ROW-3)&3] + 3.f*(hC1[(ROW-2)&3]+hC1[(ROW-1)&3]) + hC1[(ROW)&3]) * 0.125f; \
        *(unsigned*)(blds + _rb + o2) = (unsigned)f2bf(vC0) | ((unsigned)f2bf(vC1) << 16); \
    }                                                                          \
}

__global__ __launch_bounds__(256, 6)
void blur_rec(const float* __restrict__ x, unsigned char* __restrict__ bm) {
    __shared__ __align__(16) unsigned char blds[9 * 2112];   // 19008 B

    const int braw = blockIdx.x;                  // 8192
    const int bx   = ((braw & 7) << 10) | (braw >> 3);   // XCD-chunked
    const int cg   = bx & 3;
    const int tile = (bx >> 2) & 127;
    const int n    = bx >> 9;
    const int u0   = (tile >> 3) * 8;
    const int v0   = (tile & 7) * 16;
    const int tid  = threadIdx.x;
    const int a    = tid & 15;
    const int chp  = tid >> 4;
    const bool a15 = (a == 15);
    const int wc   = 2 * v0 - 2 + 2 * a;
    const bool eL  = (v0 == 0 && a == 0);         // wc = -2
    const bool eR  = (v0 == 112 && a15);          // wc = 252
    const int colLo = eL ? 0 : wc;
    const int colHi = eR ? 248 : (wc + 4);
    const float* plane0 = x + (size_t)(n * 128 + cg * 32 + 2 * chp) * 65536;
    const float* p0lo = plane0 + colLo;
    const float* p0hi = plane0 + colHi;
    const float* p1lo = p0lo + 65536;
    const float* p1hi = p0hi + 65536;
    const int xr0 = 2 * u0 - 2;

    const int J0 = 2 * a, J1 = 2 * a + 1;
    const unsigned cb2 = (unsigned)(chp & 3) * 4u;
    const unsigned o0 = (unsigned)((J0 ^ ((J0 >> 1) & 1)) * 64)
                      + ((((unsigned)chp >> 2) ^ (((unsigned)J0 >> 2) & 3u)) << 4) + cb2;
    const unsigned o1 = (unsigned)((J1 ^ ((J1 >> 1) & 1)) * 64)
                      + ((((unsigned)chp >> 2) ^ (((unsigned)J1 >> 2) & 3u)) << 4) + cb2;
    const unsigned o2 = 2048u + (((unsigned)chp >> 2) << 4) + cb2;

    unsigned char* dst = bm + (size_t)bx * 35904u;
    float hA0[4], hB0[4], hC0[4], hA1[4], hB1[4], hC1[4];

    // ---- phase 1: out rows 0..8 (i = 0..11) ----
    BRW(0) BRW(1) BRW(2)
    BRW(3)  BWV(3, 0)   BRW(4)  BWV(4, 1)   BRW(5)  BWV(5, 2)
    BRW(6)  BWV(6, 3)   BRW(7)  BWV(7, 4)   BRW(8)  BWV(8, 5)
    BRW(9)  BWV(9, 6)   BRW(10) BWV(10, 7)  BRW(11) BWV(11, 8)
    __syncthreads();
    #pragma unroll
    for (int k = 0; k < 5; ++k) {
        int sl = tid + 256 * k;
        if (sl < 1188)
            *(u32x4*)(dst + (unsigned)sl * 16u) = *(const u32x4*)(blds + (unsigned)sl * 16u);
    }
    __syncthreads();
    // ---- phase 2: out rows 9..16 (i = 12..19), LDS rows reused ----
    BRW(12) BWV(12, 0)  BRW(13) BWV(13, 1)  BRW(14) BWV(14, 2)
    BRW(15) BWV(15, 3)  BRW(16) BWV(16, 4)  BRW(17) BWV(17, 5)
    BRW(18) BWV(18, 6)  BRW(19) BWV(19, 7)
    __syncthreads();
    unsigned char* dst2 = dst + 19008u;
    #pragma unroll
    for (int k = 0; k < 5; ++k) {
        int sl = tid + 256 * k;
        if (sl < 1056)
            *(u32x4*)(dst2 + (unsigned)sl * 16u) = *(const u32x4*)(blds + (unsigned)sl * 16u);
    }
}

// ---------------- stage 2: MFMA conv; 8 waves = 8 oc-blocks, acc[8][2] ----------------
#define MF __builtin_amdgcn_mfma_f32_16x16x32_bf16
#define WLOAD2(S0, S1, KOFF) {                                                 \
    const unsigned short* _wn = wbase + (size_t)(KOFF) * 8192;                 \
    S0 = *(const bf16x8*)(_wn); S1 = *(const bf16x8*)(_wn + 512);              \
}
#define CSTEP8(BUF, ADRS, R, S0, S1) {                                         \
    const unsigned char* _ab = lds + (BUF) + (ADRS) + (R) * 2112;              \
    bf16x8 a0 = *(const bf16x8*)(_ab);                                         \
    bf16x8 a1 = *(const bf16x8*)(_ab +  4224);                                 \
    bf16x8 a2 = *(const bf16x8*)(_ab +  8448);                                 \
    bf16x8 a3 = *(const bf16x8*)(_ab + 12672);                                 \
    bf16x8 a4 = *(const bf16x8*)(_ab + 16896);                                 \
    bf16x8 a5 = *(const bf16x8*)(_ab + 21120);                                 \
    bf16x8 a6 = *(const bf16x8*)(_ab + 25344);                                 \
    bf16x8 a7 = *(const bf16x8*)(_ab + 29568);                                 \
    __builtin_amdgcn_s_setprio(1);                                             \
    acc[0][0]=MF(a0,S0,acc[0][0],0,0,0); acc[0][1]=MF(a0,S1,acc[0][1],0,0,0);  \
    acc[1][0]=MF(a1,S0,acc[1][0],0,0,0); acc[1][1]=MF(a1,S1,acc[1][1],0,0,0);  \
    acc[2][0]=MF(a2,S0,acc[2][0],0,0,0); acc[2][1]=MF(a2,S1,acc[2][1],0,0,0);  \
    acc[3][0]=MF(a3,S0,acc[3][0],0,0,0); acc[3][1]=MF(a3,S1,acc[3][1],0,0,0);  \
    acc[4][0]=MF(a4,S0,acc[4][0],0,0,0); acc[4][1]=MF(a4,S1,acc[4][1],0,0,0);  \
    acc[5][0]=MF(a5,S0,acc[5][0],0,0,0); acc[5][1]=MF(a5,S1,acc[5][1],0,0,0);  \
    acc[6][0]=MF(a6,S0,acc[6][0],0,0,0); acc[6][1]=MF(a6,S1,acc[6][1],0,0,0);  \
    acc[7][0]=MF(a7,S0,acc[7][0],0,0,0); acc[7][1]=MF(a7,S1,acc[7][1],0,0,0);  \
    __builtin_amdgcn_s_setprio(0);                                             \
}
#define CHUNK8(BUF, BASE, A0,A1, B0,B1)                                        \
    CSTEP8(BUF, adr0, 0, A0,A1) WLOAD2(A0,A1, (BASE)+2)                        \
    CSTEP8(BUF, adr1, 0, B0,B1) WLOAD2(B0,B1, (BASE)+3)                        \
    CSTEP8(BUF, adr2, 0, A0,A1) WLOAD2(A0,A1, (BASE)+4)                        \
    CSTEP8(BUF, adr0, 1, B0,B1) WLOAD2(B0,B1, (BASE)+5)                        \
    CSTEP8(BUF, adr1, 1, A0,A1) WLOAD2(A0,A1, (BASE)+6)                        \
    CSTEP8(BUF, adr2, 1, B0,B1) WLOAD2(B0,B1, (BASE)+7)                        \
    CSTEP8(BUF, adr0, 2, A0,A1) WLOAD2(A0,A1, (BASE)+8)                        \
    CSTEP8(BUF, adr1, 2, B0,B1) WLOAD2(B0,B1, (BASE)+9)                        \
    CSTEP8(BUF, adr2, 2, A0,A1) WLOAD2(A0,A1, (BASE)+10)
#define CHUNK8_LAST(BUF, BASE, A0,A1, B0,B1)                                   \
    CSTEP8(BUF, adr0, 0, A0,A1) WLOAD2(A0,A1, (BASE)+2)                        \
    CSTEP8(BUF, adr1, 0, B0,B1) WLOAD2(B0,B1, (BASE)+3)                        \
    CSTEP8(BUF, adr2, 0, A0,A1) WLOAD2(A0,A1, (BASE)+4)                        \
    CSTEP8(BUF, adr0, 1, B0,B1) WLOAD2(B0,B1, (BASE)+5)                        \
    CSTEP8(BUF, adr1, 1, A0,A1) WLOAD2(A0,A1, (BASE)+6)                        \
    CSTEP8(BUF, adr2, 1, B0,B1) WLOAD2(B0,B1, (BASE)+7)                        \
    CSTEP8(BUF, adr0, 2, A0,A1) WLOAD2(A0,A1, (BASE)+8)                        \
    CSTEP8(BUF, adr1, 2, B0,B1)                                                \
    CSTEP8(BUF, adr2, 2, A0,A1)

__global__ __launch_bounds__(512, 4)
void conv_stage2(const unsigned char* __restrict__ bm, const unsigned short* __restrict__ wp,
                 const float* __restrict__ bias, float* __restrict__ out) {
    __shared__ __align__(16) unsigned char lds[2 * 35904];

    const int bx = blockIdx.x;
    const int n  = bx >> 7;
    const int tt = bx & 127;
    const int u0 = (tt >> 3) * 8;
    const int v0 = (tt & 7) * 16;

    const int tid  = threadIdx.x;
    const int lane = tid & 63;
    const int wid  = tid >> 6;       // oc block: oc in [wid*32, wid*32+32)
    const int g    = lane >> 4;
    const int wq   = lane & 15;

    const unsigned char* rec = bm + (size_t)((n * 128 + tt) * 4) * 35904u;

#define STAGE(BUF, CG) {                                                       \
    const unsigned char* _src = rec + (size_t)(CG) * 35904u;                   \
    _Pragma("unroll")                                                          \
    for (int k = 0; k < 4; ++k)                                                \
        g2l16(_src + (unsigned)(tid + 512 * k) * 16u,                          \
              lds + (BUF) + (unsigned)(tid + 512 * k) * 16u);                  \
    if (tid < 196)                                                             \
        g2l16(_src + (unsigned)(tid + 2048) * 16u,                             \
              lds + (BUF) + (unsigned)(tid + 2048) * 16u);                     \
}

    // A-frag bases per s (granule swizzle bj^((bj>>1)&1), slot g^((bj>>2)&3))
    unsigned adr0, adr1, adr2;
    {
        #pragma unroll
        for (int s = 0; s < 3; ++s) {
            unsigned bj = 2u * (unsigned)wq + (unsigned)s;
            unsigned av = (bj ^ ((bj >> 1) & 1u)) * 64u
                        + (((unsigned)g ^ ((bj >> 2) & 3u)) << 4);
            if (s == 0) adr0 = av; else if (s == 1) adr1 = av; else adr2 = av;
        }
    }

    const unsigned short* wbase = wp + (size_t)(wid * 32 + wq) * 32 + g * 8;
    bf16x8 WA0, WA1, WB0, WB1;
    WLOAD2(WA0, WA1, 0)
    WLOAD2(WB0, WB1, 1)

    f32x4 acc[8][2];
    #pragma unroll
    for (int i = 0; i < 8; ++i) {
        acc[i][0] = (f32x4){0.f, 0.f, 0.f, 0.f};
        acc[i][1] = (f32x4){0.f, 0.f, 0.f, 0.f};
    }

    STAGE(0, 0)
    __syncthreads();

    STAGE(35904, 1)
    CHUNK8(0, 0, WA0, WA1, WB0, WB1)
    __syncthreads();

    STAGE(0, 2)
    CHUNK8(35904, 9, WB0, WB1, WA0, WA1)
    __syncthreads();

    STAGE(35904, 3)
    CHUNK8(0, 18, WA0, WA1, WB0, WB1)
    __syncthreads();

    CHUNK8_LAST(35904, 27, WB0, WB1, WA0, WA1)

    // epilogue: u = u0 + mf, v = v0 + 4g + i, oc = wid*32 + nf*16 + wq
    const float gain = 1.4142135623730951f;
    #pragma unroll
    for (int nf = 0; nf < 2; ++nf) {
        const int ocg = wid * 32 + nf * 16 + wq;
        const float bb = bias[ocg];
        #pragma unroll
        for (int mf = 0; mf < 8; ++mf) {
            f32x4 o;
            #pragma unroll
            for (int i = 0; i < 4; ++i) {
                float z = acc[mf][nf][i] + bb;
                z = (z >= 0.f ? z : 0.2f * z) * gain;
                o[i] = fminf(fmaxf(z, -256.f), 256.f);
            }
            *(f32x4*)(out + (((size_t)n * 256 + ocg) * 128 + (u0 + mf)) * 128 + v0 + 4 * g) = o;
        }
    }
}

// ======================= Fallback: proven R5 fused kernel =======================
#define FROW(row) {                                                            \
    int xr  = xr0 + (row);                                                     \
    int xrc = xr < 0 ? 0 : (xr > 255 ? 255 : xr);                              \
    float rm = (xr == xrc) ? 0.125f : 0.0f;                                    \
    const float* p = q + (xrc << 8);                                           \
    f32x4 lo; f32x2 hi;                                                        \
    __builtin_memcpy(&lo, p, 16);                                              \
    __builtin_memcpy(&hi, p + 4, 8);                                           \
    hA[(row) & 3] = (lo.x + 3.f * (lo.y + lo.z) + lo.w) * rm;                  \
    hB[(row) & 3] = (lo.y + 3.f * (lo.z + lo.w) + hi.x) * rm;                  \
    hC[(row) & 3] = (lo.z + 3.f * (lo.w + hi.x) + hi.y) * rm;                  \
}
#define SROW(row) {                                                            \
    int xr = xr0 + (row);                                                      \
    float wv0=0.f,wv1=0.f,wv2=0.f,wv3=0.f,wv4=0.f,wv5=0.f;                     \
    if ((unsigned)xr < 256u) {                                                 \
        const float* p = q + (xr << 8);                                        \
        if ((unsigned)(wc + 0) < 256u) wv0 = p[0];                             \
        if ((unsigned)(wc + 1) < 256u) wv1 = p[1];                             \
        if ((unsigned)(wc + 2) < 256u) wv2 = p[2];                             \
        if ((unsigned)(wc + 3) < 256u) wv3 = p[3];                             \
        if ((unsigned)(wc + 4) < 256u) wv4 = p[4];                             \
        if ((unsigned)(wc + 5) < 256u) wv5 = p[5];                             \
    }                                                                          \
    hA[(row) & 3] = (wv0 + 3.f * (wv1 + wv2) + wv3) * 0.125f;                  \
    hB[(row) & 3] = (wv1 + 3.f * (wv2 + wv3) + wv4) * 0.125f;                  \
    hC[(row) & 3] = (wv2 + 3.f * (wv3 + wv4) + wv5) * 0.125f;                  \
}
#define VROW(row) {                                                            \
    float bv0 = (hA[(row - 3) & 3] + 3.f * (hA[(row - 2) & 3] + hA[(row - 1) & 3]) + hA[(row) & 3]) * 0.125f; \
    float bv1 = (hB[(row - 3) & 3] + 3.f * (hB[(row - 2) & 3] + hB[(row - 1) & 3]) + hB[(row) & 3]) * 0.125f; \
    unsigned rb = (unsigned)(row - 3) * 2640u;                                 \
    *(unsigned short*)(flds + rb + o0) = f2bf(bv0);                            \
    *(unsigned short*)(flds + rb + o1) = f2bf(bv1);                            \
    if (a == 15) {                                                             \
        float bv2 = (hC[(row - 3) & 3] + 3.f * (hC[(row - 2) & 3] + hC[(row - 1) & 3]) + hC[(row) & 3]) * 0.125f; \
        *(unsigned short*)(flds + rb + o2) = f2bf(bv2);                        \
    }                                                                          \
}
__global__ __launch_bounds__(512, 4)
void conv_blur_mfma(const float* __restrict__ x, const unsigned short* __restrict__ wp,
                    const float* __restrict__ bias, float* __restrict__ out) {
    __shared__ __align__(16) unsigned char flds[17 * 33 * 80];
    const int bx = blockIdx.x;
    const int n  = bx >> 7;
    const int tt = bx & 127;
    const int u0 = (tt >> 3) * 8;
    const int v0 = (tt & 7) * 16;
    const int tid  = threadIdx.x;
    const int lane = tid & 63;
    const int wid  = tid >> 6;
    const int wm   = wid >> 2;
    const int wn   = wid & 3;
    const int g    = lane >> 4;
    const int wq   = lane & 15;
    const int a   = tid & 15;
    const int chl = tid >> 4;
    const int wc  = 2 * v0 - 2 + 2 * a;
    const bool edge = (v0 == 0 && a == 0) || (v0 == 112 && a == 15);
    const float* planeBase = x + (size_t)(n * 128 + chl) * 65536;
    const int xr0 = 2 * u0 - 2;
    const unsigned chpart = (unsigned)(((chl >> 1) & 3) * 4 + (chl & 1) * 2);
    const unsigned q4 = (unsigned)(chl >> 3);
    const int c0 = 2 * a;
    const unsigned o0 = (unsigned)(c0 + 0) * 80u + ((q4 ^ (((unsigned)(c0 + 0) >> 3) & 3u)) << 4) + chpart;
    const unsigned o1 = (unsigned)(c0 + 1) * 80u + ((q4 ^ (((unsigned)(c0 + 1) >> 3) & 3u)) << 4) + chpart;
    const unsigned o2 = (unsigned)(c0 + 2) * 80u + ((q4 ^ (((unsigned)(c0 + 2) >> 3) & 3u)) << 4) + chpart;
    const unsigned short* wpL = wp + (size_t)(wn * 64 + wq) * 32 + g * 8;
    f32x4 acc[4][4];
    #pragma unroll
    for (int i = 0; i < 4; ++i)
        #pragma unroll
        for (int j = 0; j < 4; ++j)
            acc[i][j] = (f32x4){0.f, 0.f, 0.f, 0.f};
    for (int ch = 0; ch < 4; ++ch) {
        const float* q = planeBase + (size_t)ch * 32 * 65536 + wc;
        float hA[4], hB[4], hC[4];
        if (!edge) { FROW(0) FROW(1) FROW(2) }
        else       { SROW(0) SROW(1) SROW(2) }
        __syncthreads();
        if (!edge) {
            #pragma unroll
            for (int row = 3; row < 20; ++row) { FROW(row) VROW(row) }
        } else {
            #pragma unroll
            for (int row = 3; row < 20; ++row) { SROW(row) VROW(row) }
        }
        __syncthreads();
        const unsigned short* wpc = wpL + (size_t)ch * 9 * 8192;
        #pragma unroll 1
        for (int r = 0; r < 3; ++r) {
            #pragma unroll 1
            for (int s = 0; s < 3; ++s) {
                bf16x8 b0 = *(const bf16x8*)(wpc + 0 * 512);
                bf16x8 b1 = *(const bf16x8*)(wpc + 1 * 512);
                bf16x8 b2 = *(const bf16x8*)(wpc + 2 * 512);
                bf16x8 b3 = *(const bf16x8*)(wpc + 3 * 512);
                wpc += 8192;
                int bj = 2 * wq + s;
                unsigned cb = (unsigned)bj * 80u + ((unsigned)(g ^ ((bj >> 3) & 3)) << 4);
                #pragma unroll
                for (int mf = 0; mf < 4; ++mf) {
                    int bi = 2 * (wm * 4 + mf) + r;
                    bf16x8 afrag = *(const bf16x8*)(flds + (unsigned)bi * 2640u + cb);
                    acc[mf][0] = MF(afrag, b0, acc[mf][0], 0, 0, 0);
                    acc[mf][1] = MF(afrag, b1, acc[mf][1], 0, 0, 0);
                    acc[mf][2] = MF(afrag, b2, acc[mf][2], 0, 0, 0);
                    acc[mf][3] = MF(afrag, b3, acc[mf][3], 0, 0, 0);
                }
            }
        }
    }
    const float gain = 1.4142135623730951f;
    #pragma unroll
    for (int nf = 0; nf < 4; ++nf) {
        int ocg = wn * 64 + nf * 16 + wq;
        float bv = bias[ocg];
        #pragma unroll
        for (int mf = 0; mf < 4; ++mf) {
            int u = u0 + wm * 4 + mf;
            f32x4 o;
            #pragma unroll
            for (int i = 0; i < 4; ++i) {
                float z = acc[mf][nf][i] + bv;
                z = (z >= 0.f ? z : 0.2f * z) * gain;
                o[i] = fminf(fmaxf(z, -256.f), 256.f);
            }
            *(f32x4*)(out + (((size_t)n * 256 + ocg) * 128 + u) * 128 + v0 + 4 * g) = o;
        }
    }
}

extern "C" void kernel_launch(void* const* d_in, const int* in_sizes, int n_in,
                              void* d_out, int out_size, void* d_ws, size_t ws_size,
                              hipStream_t stream) {
    const float* x    = (const float*)d_in[0];
    const float* w    = (const float*)d_in[1];
    const float* bias = (const float*)d_in[2];
    unsigned short* wp = (unsigned short*)d_ws;           // 589,824 B
    float* out = (float*)d_out;

    const size_t BM_BYTES = (size_t)8192 * 35904u;        // 294,076,416
    const size_t NEED = 589824u + BM_BYTES;
    prep_weights<<<1152, 256, 0, stream>>>(w, wp);
    if (ws_size >= NEED) {
        unsigned char* bm = (unsigned char*)d_ws + 589824;
        blur_rec<<<8192, 256, 0, stream>>>(x, bm);
        conv_stage2<<<2048, 512, 0, stream>>>(bm, wp, bias, out);
    } else {
        conv_blur_mfma<<<2048, 512, 0, stream>>>(x, wp, bias, out);
    }
}